// Round 1
// baseline (4248.282 us; speedup 1.0000x reference)
//
#include <hip/hip_runtime.h>
#include <cstdint>
#include <cstddef>

#define NN 16384
#define EE 49152
#define BB 256
// D=256, G=16, 16 channels/group, HD=16

static constexpr size_t ND = (size_t)NN * 256;

// ---------------- elementwise / setup kernels ----------------

__global__ __launch_bounds__(256) void zero_f_kernel(float* __restrict__ p, size_t n) {
  size_t i = (size_t)blockIdx.x * 256 + threadIdx.x;
  if (i < n) p[i] = 0.f;
}
__global__ __launch_bounds__(256) void zero_i_kernel(int* __restrict__ p, int n) {
  int i = blockIdx.x * 256 + threadIdx.x;
  if (i < n) p[i] = 0;
}
__global__ __launch_bounds__(256) void count_deg_kernel(const int* __restrict__ dst, int* __restrict__ cnt, int e) {
  int i = blockIdx.x * 256 + threadIdx.x;
  if (i < e) atomicAdd(&cnt[dst[i]], 1);
}
__global__ __launch_bounds__(256) void clip_deg_kernel(int* __restrict__ deg, int n) {
  int i = blockIdx.x * 256 + threadIdx.x;
  if (i < n) { int v = deg[i] - 1; deg[i] = v < 0 ? 0 : (v > 3 ? 3 : v); }
}
// batch is sorted; goff[b] = first node index of graph b, goff[BB] = NN
__global__ __launch_bounds__(256) void goff_kernel(const int* __restrict__ batch, int* __restrict__ goff, int n, int b) {
  int i = blockIdx.x * 256 + threadIdx.x;
  if (i > n) return;
  int cur = (i < n) ? batch[i] : b;
  int prev = (i == 0) ? -1 : batch[i - 1];
  for (int x = prev + 1; x <= cur; x++) goff[x] = i;
}
__global__ __launch_bounds__(256) void add3_kernel(float* __restrict__ dst,
    const float* __restrict__ a, const float* __restrict__ b, size_t n) {
  size_t i = (size_t)blockIdx.x * 256 + threadIdx.x;
  if (i < n) dst[i] = a[i] + b[i];
}
// x_out += exp(scale[deg[n]][c]) * x_raw
__global__ __launch_bounds__(256) void deg_scaled_add_kernel(float* __restrict__ xo,
    const float* __restrict__ xr, const float* __restrict__ sc, const int* __restrict__ deg) {
  size_t i = (size_t)blockIdx.x * 256 + threadIdx.x;
  int n = (int)(i >> 8), c = (int)(i & 255);
  xo[i] += expf(sc[deg[n] * 256 + c]) * xr[i];
}
// h_out += exp(vs[c]) * vout[batch[n]][c]
__global__ __launch_bounds__(256) void bcast_add_kernel(float* __restrict__ ho,
    const float* __restrict__ vo, const float* __restrict__ vs, const int* __restrict__ batch) {
  size_t i = (size_t)blockIdx.x * 256 + threadIdx.x;
  int n = (int)(i >> 8), c = (int)(i & 255);
  ho[i] += expf(vs[c]) * vo[(size_t)batch[n] * 256 + c];
}

// ---------------- initial edge / node features ----------------

// one 64-lane wave per edge: h2d (3 bond tables), gaussian h3d, sigmoid gate, scatter h_e by dst
__global__ __launch_bounds__(256) void edge_feat_kernel(
    const int* __restrict__ eattr, const int* __restrict__ dst,
    const float* __restrict__ edist, const float* __restrict__ bond2d,
    const float* __restrict__ gmeans, const float* __restrict__ gstds,
    const float* __restrict__ attn_w, const float* __restrict__ attn_b,
    float* __restrict__ tmp) {
  int lane = threadIdx.x & 63;
  int e = blockIdx.x * 4 + (threadIdx.x >> 6);
  if (e >= EE) return;
  int a0 = eattr[e * 3 + 0], a1 = eattr[e * 3 + 1], a2 = eattr[e * 3 + 2];
  float dist = edist[e];
  int d = dst[e];
  const float SQ2PI = sqrtf(2.0f * 3.14159f);
  float h2[4], h3[4];
  float part = 0.f;
#pragma unroll
  for (int i = 0; i < 4; i++) {
    int c = lane + 64 * i;
    h2[i] = bond2d[a0 * 256 + c] + bond2d[2048 + a1 * 256 + c] + bond2d[4096 + a2 * 256 + c];
    float sd = fabsf(gstds[c]) + 0.01f;
    float df = (dist - gmeans[c]) / sd;
    h3[i] = expf(-0.5f * df * df) / (SQ2PI * sd);
    part += attn_w[c] * h2[i] + attn_w[256 + c] * h3[i];
  }
#pragma unroll
  for (int off = 32; off > 0; off >>= 1) part += __shfl_xor(part, off);
  float wg = 1.f / (1.f + expf(-(part + attn_b[0])));
#pragma unroll
  for (int i = 0; i < 4; i++) {
    int c = lane + 64 * i;
    atomicAdd(&tmp[(size_t)d * 256 + c], wg * h2[i] + (1.f - wg) * h3[i]);
  }
}

// h_in = sum_f atom_emb[f][xf[n][f]] + exp(scale_both[deg[n]]) * tmp
__global__ __launch_bounds__(256) void atom_finish_kernel(
    const int* __restrict__ xf, const float* __restrict__ emb,
    const float* __restrict__ scale_both, const int* __restrict__ deg,
    const float* __restrict__ tmp, float* __restrict__ h_in) {
  size_t i = (size_t)blockIdx.x * 256 + threadIdx.x;
  int n = (int)(i >> 8), c = (int)(i & 255);
  float acc = 0.f;
#pragma unroll
  for (int f = 0; f < 9; f++) {
    int v = xf[n * 9 + f];
    acc += emb[((size_t)(f * 128 + v)) * 256 + c];
  }
  h_in[i] = acc + expf(scale_both[deg[n] * 256 + c]) * tmp[i];
}

// ---------------- generic fp32 GEMM: C[M,256] = A[M,K] @ W[256,K]^T ----------------
// MODE 0: store (+bias); MODE 1: atomicAdd into C[ridx[row]] (+bias); MODE 2: C += exp(scale[col])*(acc+bias)
template <int MODE>
__global__ __launch_bounds__(256) void gemm_kernel(
    const float* __restrict__ A, const float* __restrict__ W,
    const float* __restrict__ bias, const float* __restrict__ scale,
    const int* __restrict__ ridx, float* __restrict__ C, int M, int K) {
  __shared__ float As[16][65];
  __shared__ float Ws[16][65];
  const int tid = threadIdx.x;
  const int row0 = blockIdx.x * 64;
  const int col0 = blockIdx.y * 64;
  const int tx = tid & 15, ty = tid >> 4;
  float acc[4][4] = {};
  for (int k0 = 0; k0 < K; k0 += 16) {
#pragma unroll
    for (int i = 0; i < 4; i++) {
      int idx = tid + i * 256;
      int m = idx >> 4, kk = idx & 15;
      As[kk][m] = A[(size_t)(row0 + m) * K + (k0 + kk)];
      Ws[kk][m] = W[(size_t)(col0 + m) * K + (k0 + kk)];
    }
    __syncthreads();
#pragma unroll
    for (int kk = 0; kk < 16; kk++) {
      float a[4], b[4];
#pragma unroll
      for (int i = 0; i < 4; i++) a[i] = As[kk][ty * 4 + i];
#pragma unroll
      for (int j = 0; j < 4; j++) b[j] = Ws[kk][tx * 4 + j];
#pragma unroll
      for (int i = 0; i < 4; i++)
#pragma unroll
        for (int j = 0; j < 4; j++) acc[i][j] += a[i] * b[j];
    }
    __syncthreads();
  }
#pragma unroll
  for (int i = 0; i < 4; i++) {
    int row = row0 + ty * 4 + i;
#pragma unroll
    for (int j = 0; j < 4; j++) {
      int col = col0 + tx * 4 + j;
      float v = acc[i][j];
      if (bias) v += bias[col];
      if (MODE == 0) {
        C[(size_t)row * 256 + col] = v;
      } else if (MODE == 1) {
        atomicAdd(&C[(size_t)ridx[row] * 256 + col], v);
      } else {
        C[(size_t)row * 256 + col] += expf(scale[col]) * v;
      }
    }
  }
}

// ---------------- conv edge front: gather + bond + GN + glin(gate/val) + product ----------------
// thread = (edge, group); weights transposed in LDS so lanes (varying g) hit consecutive banks
__global__ __launch_bounds__(256) void conv_edge_kernel(
    const float* __restrict__ xp, const int* __restrict__ eattr,
    const int* __restrict__ src, const int* __restrict__ dst,
    const float* __restrict__ bond_emb, const float* __restrict__ gate_w,
    const float* __restrict__ val_w, float* __restrict__ out) {
  __shared__ float sb[6144];  // [3][8][256]
  __shared__ float sg[4096];  // transposed [o][i][g]
  __shared__ float sv[4096];
  int tid = threadIdx.x;
  for (int i = tid; i < 6144; i += 256) sb[i] = bond_emb[i];
  for (int i = tid; i < 4096; i += 256) {
    int g = i >> 8, o = (i >> 4) & 15, ii = i & 15;
    int t = (o * 16 + ii) * 16 + g;
    sg[t] = gate_w[i];
    sv[t] = val_w[i];
  }
  __syncthreads();
  int idx = blockIdx.x * 256 + tid;
  int e = idx >> 4, g = idx & 15;
  int a0 = eattr[e * 3 + 0], a1 = eattr[e * 3 + 1], a2 = eattr[e * 3 + 2];
  int d = dst[e], s = src[e];
  const float* xd = &xp[(size_t)d * 256 + g * 16];
  const float* xs = &xp[(size_t)s * 256 + g * 16];
  float xg[16], xv[16];
  float mg = 0.f, mv = 0.f;
#pragma unroll
  for (int i = 0; i < 16; i++) {
    float bo = sb[a0 * 256 + g * 16 + i] + sb[2048 + a1 * 256 + g * 16 + i] + sb[4096 + a2 * 256 + g * 16 + i];
    xg[i] = xd[i] + bo;
    xv[i] = xs[i] + bo;
    mg += xg[i];
    mv += xv[i];
  }
  mg *= (1.f / 16.f);
  mv *= (1.f / 16.f);
  float vg = 0.f, vv = 0.f;
#pragma unroll
  for (int i = 0; i < 16; i++) {
    float dg_ = xg[i] - mg, dv_ = xv[i] - mv;
    vg += dg_ * dg_;
    vv += dv_ * dv_;
  }
  float rg = rsqrtf(vg * (1.f / 16.f) + 1e-5f);
  float rv = rsqrtf(vv * (1.f / 16.f) + 1e-5f);
#pragma unroll
  for (int i = 0; i < 16; i++) {
    xg[i] = (xg[i] - mg) * rg;
    xv[i] = (xv[i] - mv) * rv;
  }
  float* op = &out[(size_t)e * 256 + g * 16];
#pragma unroll
  for (int o = 0; o < 16; o++) {
    float ag = 0.f, av = 0.f;
#pragma unroll
    for (int i = 0; i < 16; i++) {
      ag += xg[i] * sg[(o * 16 + i) * 16 + g];
      av += xv[i] * sv[(o * 16 + i) * 16 + g];
    }
    op[o] = fmaxf(ag, 0.f) * av;
  }
}

// ---------------- glb middle: GN + glin(gate/val, DOUT per group) + relu*mul ----------------
template <int DOUT>
__global__ __launch_bounds__(256) void glb_mid_kernel(
    const float* __restrict__ X, const float* __restrict__ gate_w,
    const float* __restrict__ val_w, float* __restrict__ out) {
  __shared__ float sg[16 * DOUT * 16];
  __shared__ float sv[16 * DOUT * 16];
  int tid = threadIdx.x;
  for (int i = tid; i < 16 * DOUT * 16; i += 256) {
    int g = i / (DOUT * 16), rem = i % (DOUT * 16), o = rem >> 4, ii = rem & 15;
    int t = (o * 16 + ii) * 16 + g;
    sg[t] = gate_w[i];
    sv[t] = val_w[i];
  }
  __syncthreads();
  int idx = blockIdx.x * 256 + tid;
  int n = idx >> 4, g = idx & 15;
  float x[16];
  float m = 0.f;
#pragma unroll
  for (int i = 0; i < 16; i++) {
    x[i] = X[(size_t)n * 256 + g * 16 + i];
    m += x[i];
  }
  m *= (1.f / 16.f);
  float v = 0.f;
#pragma unroll
  for (int i = 0; i < 16; i++) {
    float d_ = x[i] - m;
    v += d_ * d_;
  }
  float r = rsqrtf(v * (1.f / 16.f) + 1e-5f);
#pragma unroll
  for (int i = 0; i < 16; i++) x[i] = (x[i] - m) * r;
  float* op = &out[(size_t)n * (16 * DOUT) + g * DOUT];
  for (int o = 0; o < DOUT; o++) {
    float ag = 0.f, av = 0.f;
#pragma unroll
    for (int i = 0; i < 16; i++) {
      ag += x[i] * sg[(o * 16 + i) * 16 + g];
      av += x[i] * sv[(o * 16 + i) * 16 + g];
    }
    op[o] = fmaxf(ag, 0.f) * av;
  }
}

// standalone GroupNorm (in place), thread = (row, group)
__global__ __launch_bounds__(256) void gn_kernel(float* __restrict__ X) {
  int idx = blockIdx.x * 256 + threadIdx.x;
  int n = idx >> 4, g = idx & 15;
  float x[16];
  float m = 0.f;
#pragma unroll
  for (int i = 0; i < 16; i++) {
    x[i] = X[(size_t)n * 256 + g * 16 + i];
    m += x[i];
  }
  m *= (1.f / 16.f);
  float v = 0.f;
#pragma unroll
  for (int i = 0; i < 16; i++) {
    float d_ = x[i] - m;
    v += d_ * d_;
  }
  float r = rsqrtf(v * (1.f / 16.f) + 1e-5f);
#pragma unroll
  for (int i = 0; i < 16; i++) X[(size_t)n * 256 + g * 16 + i] = (x[i] - m) * r;
}

// ---------------- attention: per-graph xk/xv + h_att(+=) + xk_sum ----------------
__global__ __launch_bounds__(256) void att_graph_kernel(
    const float* __restrict__ xv0, const float* __restrict__ k_w,
    const float* __restrict__ v_w, const int* __restrict__ goff,
    float* __restrict__ h_att, float* __restrict__ xk_sum) {
  __shared__ float skw[8192];  // [i][o] transposed
  __shared__ float svw[8192];
  __shared__ float hatt[8192];  // [32][16][16]
  __shared__ float kx[512], vx[512], ks[512], row[256];
  int tid = threadIdx.x, b = blockIdx.x;
  for (int i = tid; i < 8192; i += 256) {
    int o = i >> 4, ii = i & 15;
    skw[ii * 512 + o] = k_w[i];
    svw[ii * 512 + o] = v_w[i];
    hatt[i] = h_att[(size_t)b * 8192 + i];
  }
  for (int i = tid; i < 512; i += 256) ks[i] = 0.f;
  __syncthreads();
  int n0 = goff[b], n1 = goff[b + 1];
  for (int n = n0; n < n1; n++) {
    row[tid] = xv0[(size_t)n * 256 + tid];
    __syncthreads();
#pragma unroll
    for (int half = 0; half < 2; half++) {
      int o = tid + half * 256;
      int g = o >> 5;
      float aK = 0.f, aV = 0.f;
#pragma unroll
      for (int i = 0; i < 16; i++) {
        float xr = row[g * 16 + i];
        aK += xr * skw[i * 512 + o];
        aV += xr * svw[i * 512 + o];
      }
      float ek = expf(aK * 0.25f);
      kx[o] = ek;
      vx[o] = aV;
      ks[o] += ek;
    }
    __syncthreads();
#pragma unroll
    for (int rep = 0; rep < 32; rep++) {
      int id = tid + rep * 256;
      int head = id >> 8, h = (id >> 4) & 15, vv_ = id & 15;
      hatt[id] += kx[head * 16 + h] * vx[head * 16 + vv_];
    }
    __syncthreads();
  }
  for (int i = tid; i < 8192; i += 256) h_att[(size_t)b * 8192 + i] = hatt[i];
  for (int i = tid; i < 512; i += 256) xk_sum[(size_t)b * 512 + i] = ks[i];
}

// per (node, head): xq, per-head normalize, att_out = (q/denom) @ h_att[b][head]
__global__ __launch_bounds__(256) void att_out_kernel(
    const float* __restrict__ xv0, const float* __restrict__ q_w,
    const float* __restrict__ xk_sum, const float* __restrict__ h_att,
    const int* __restrict__ batch, float* __restrict__ out) {
  __shared__ float sqw[8192];  // transposed [oo][i][g]
  int tid = threadIdx.x;
  for (int i = tid; i < 8192; i += 256) {
    int g = i >> 9, oo = (i >> 4) & 31, ii = i & 15;
    sqw[(oo * 16 + ii) * 16 + g] = q_w[i];
  }
  __syncthreads();
  int idx = blockIdx.x * 256 + tid;
  int n = idx >> 5, head = idx & 31;
  int b = batch[n];
  int g = head >> 1, j = head & 1;
  float x[16];
#pragma unroll
  for (int i = 0; i < 16; i++) x[i] = xv0[(size_t)n * 256 + g * 16 + i];
  float q[16];
  float denom = 0.f;
#pragma unroll
  for (int h = 0; h < 16; h++) {
    float a = 0.f;
    int oo = j * 16 + h;
#pragma unroll
    for (int i = 0; i < 16; i++) a += x[i] * sqw[(oo * 16 + i) * 16 + g];
    float e = expf(a * 0.25f);
    q[h] = e;
    denom += e * xk_sum[(size_t)b * 512 + head * 16 + h];
  }
  float inv = 1.f / denom;
  const float* ha = &h_att[((size_t)b * 32 + head) * 256];
#pragma unroll
  for (int v = 0; v < 16; v++) {
    float a = 0.f;
#pragma unroll
    for (int h = 0; h < 16; h++) a += q[h] * ha[h * 16 + v];
    out[(size_t)n * 512 + head * 16 + v] = a * inv;
  }
}

// h_virt[b] += segment_sum(h_in) over graph b
__global__ __launch_bounds__(256) void virt_seg_kernel(const float* __restrict__ h_in,
    const int* __restrict__ goff, float* __restrict__ h_virt) {
  int b = blockIdx.x, c = threadIdx.x;
  float acc = h_virt[(size_t)b * 256 + c];
  int n0 = goff[b], n1 = goff[b + 1];
  for (int n = n0; n < n1; n++) acc += h_in[(size_t)n * 256 + c];
  h_virt[(size_t)b * 256 + c] = acc;
}

// ---------------- host driver ----------------

extern "C" void kernel_launch(void* const* d_in, const int* in_sizes, int n_in,
                              void* d_out, int out_size, void* d_ws, size_t ws_size,
                              hipStream_t stream) {
  const int* x_feat = (const int*)d_in[0];
  const int* eidx = (const int*)d_in[1];
  const int* eattr = (const int*)d_in[2];
  const int* batch = (const int*)d_in[3];
  const float* edist = (const float*)d_in[5];
  const float* atom_emb = (const float*)d_in[6];
  const float* bond2d = (const float*)d_in[7];
  const float* gmeans = (const float*)d_in[8];
  const float* gstds = (const float*)d_in[9];
  const float* attn_w = (const float*)d_in[10];
  const float* attn_b = (const float*)d_in[11];
  const float* scale_both = (const float*)d_in[12];
  const float* conv_bond_emb = (const float*)d_in[13];
  const float* conv_pre_w = (const float*)d_in[14];
  const float* conv_gate_w = (const float*)d_in[15];
  const float* conv_val_w = (const float*)d_in[16];
  const float* conv_post_w = (const float*)d_in[17];
  const float* conv_post_b = (const float*)d_in[18];
  const float* conv_scale = (const float*)d_in[19];
  const float* virt_pre_w = (const float*)d_in[20];
  const float* virt_pre_b = (const float*)d_in[21];
  const float* virt_gate_w = (const float*)d_in[22];
  const float* virt_val_w = (const float*)d_in[23];
  const float* virt_post_w = (const float*)d_in[24];
  const float* virt_post_b = (const float*)d_in[25];
  const float* virt_scale = (const float*)d_in[26];
  const float* att_pre_w = (const float*)d_in[27];
  const float* att_pre_b = (const float*)d_in[28];
  const float* att_q_w = (const float*)d_in[29];
  const float* att_k_w = (const float*)d_in[30];
  const float* att_v_w = (const float*)d_in[31];
  const float* att_post_w = (const float*)d_in[32];
  const float* att_post_b = (const float*)d_in[33];
  const float* att_scale = (const float*)d_in[34];
  const float* main_pre_w = (const float*)d_in[35];
  const float* main_pre_b = (const float*)d_in[36];
  const float* main_gate_w = (const float*)d_in[37];
  const float* main_val_w = (const float*)d_in[38];
  const float* main_post_w = (const float*)d_in[39];
  const float* main_post_b = (const float*)d_in[40];

  const int* src = eidx;
  const int* dst = eidx + EE;

  float* ws = (float*)d_ws;
  float* h_in = ws;
  float* h_out = ws + ND;
  float* x_raw = ws + 2 * ND;
  float* x_out = ws + 3 * ND;  // also initial edge-scatter accumulator
  float* nodeA = ws + 4 * ND;
  float* etmp = ws + 5 * ND;  // E*256 = 3*ND; also [N,512] att_out and [N,768] main mid
  float* h_virt = ws + 8 * ND;                // B*256
  float* h_att = h_virt + 65536;              // B*32*16*16
  float* xk_sum = h_att + 2097152;            // B*512
  float* vt1 = xk_sum + 131072;               // B*256
  float* vmid = vt1 + 65536;                  // B*512
  float* vout = vmid + 131072;                // B*256
  int* deg = (int*)(vout + 65536);            // N ints
  int* goff = deg + NN;                       // B+1 ints

  auto zf = [&](float* p, size_t n) {
    zero_f_kernel<<<(int)((n + 255) / 256), 256, 0, stream>>>(p, n);
  };

  // degree + graph offsets
  zero_i_kernel<<<NN / 256, 256, 0, stream>>>(deg, NN);
  count_deg_kernel<<<EE / 256, 256, 0, stream>>>(dst, deg, EE);
  clip_deg_kernel<<<NN / 256, 256, 0, stream>>>(deg, NN);
  goff_kernel<<<(NN + 256) / 256, 256, 0, stream>>>(batch, goff, NN, BB);

  // initial node features
  zf(x_out, ND);
  edge_feat_kernel<<<EE / 4, 256, 0, stream>>>(eattr, dst, edist, bond2d, gmeans, gstds,
                                               attn_w, attn_b, x_out);
  atom_finish_kernel<<<(int)(ND / 256), 256, 0, stream>>>(x_feat, atom_emb, scale_both, deg,
                                                          x_out, h_in);
  zf(h_virt, 65536);
  zf(h_att, 2097152);

  for (int l = 0; l < 2; l++) {
    // ---- ConvMessage ----
    zf(x_out, ND);
    const float* cur_raw = h_in;
    for (int k = 0; k < 4; k++) {
      if (k == 2) {
        add3_kernel<<<(int)(ND / 256), 256, 0, stream>>>(x_raw, h_in, x_out, ND);
        zf(x_out, ND);
        cur_raw = x_raw;
      }
      size_t lk = (size_t)(l * 4 + k);
      gemm_kernel<0><<<dim3(NN / 64, 4), 256, 0, stream>>>(
          cur_raw, conv_pre_w + lk * 65536, nullptr, nullptr, nullptr, nodeA, NN, 256);
      conv_edge_kernel<<<EE * 16 / 256, 256, 0, stream>>>(
          nodeA, eattr, src, dst, conv_bond_emb + lk * 6144,
          conv_gate_w + lk * 4096, conv_val_w + lk * 4096, etmp);
      zf(x_raw, ND);
      gemm_kernel<1><<<dim3(EE / 64, 4), 256, 0, stream>>>(
          etmp, conv_post_w + lk * 65536, conv_post_b + lk * 256, nullptr, dst, x_raw, EE, 256);
      cur_raw = x_raw;
      deg_scaled_add_kernel<<<(int)(ND / 256), 256, 0, stream>>>(
          x_out, x_raw, conv_scale + lk * 1024, deg);
    }
    add3_kernel<<<(int)(ND / 256), 256, 0, stream>>>(h_out, h_in, x_out, ND);

    // ---- VirtMessage ----
    virt_seg_kernel<<<BB, 256, 0, stream>>>(h_in, goff, h_virt);
    gemm_kernel<0><<<dim3(BB / 64, 4), 256, 0, stream>>>(
        h_virt, virt_pre_w + (size_t)l * 65536, virt_pre_b + (size_t)l * 256,
        nullptr, nullptr, vt1, BB, 256);
    glb_mid_kernel<32><<<BB * 16 / 256, 256, 0, stream>>>(
        vt1, virt_gate_w + (size_t)l * 8192, virt_val_w + (size_t)l * 8192, vmid);
    gemm_kernel<0><<<dim3(BB / 64, 4), 256, 0, stream>>>(
        vmid, virt_post_w + (size_t)l * 131072, virt_post_b + (size_t)l * 256,
        nullptr, nullptr, vout, BB, 512);
    bcast_add_kernel<<<(int)(ND / 256), 256, 0, stream>>>(
        h_out, vout, virt_scale + (size_t)l * 256, batch);

    // ---- AttMessage ----
    gemm_kernel<0><<<dim3(NN / 64, 4), 256, 0, stream>>>(
        h_in, att_pre_w + (size_t)l * 65536, att_pre_b + (size_t)l * 256,
        nullptr, nullptr, nodeA, NN, 256);
    gn_kernel<<<NN * 16 / 256, 256, 0, stream>>>(nodeA);
    att_graph_kernel<<<BB, 256, 0, stream>>>(
        nodeA, att_k_w + (size_t)l * 8192, att_v_w + (size_t)l * 8192, goff, h_att, xk_sum);
    att_out_kernel<<<NN * 32 / 256, 256, 0, stream>>>(
        nodeA, att_q_w + (size_t)l * 8192, xk_sum, h_att, batch, etmp);
    gemm_kernel<2><<<dim3(NN / 64, 4), 256, 0, stream>>>(
        etmp, att_post_w + (size_t)l * 131072, att_post_b + (size_t)l * 256,
        att_scale + (size_t)l * 256, nullptr, h_out, NN, 512);

    // ---- main gated block ----
    gemm_kernel<0><<<dim3(NN / 64, 4), 256, 0, stream>>>(
        h_out, main_pre_w + (size_t)l * 65536, main_pre_b + (size_t)l * 256,
        nullptr, nullptr, nodeA, NN, 256);
    glb_mid_kernel<48><<<NN * 16 / 256, 256, 0, stream>>>(
        nodeA, main_gate_w + (size_t)l * 12288, main_val_w + (size_t)l * 12288, etmp);
    float* hdst = (l == 1) ? (float*)d_out : h_in;
    gemm_kernel<0><<<dim3(NN / 64, 4), 256, 0, stream>>>(
        etmp, main_post_w + (size_t)l * 196608, main_post_b + (size_t)l * 256,
        nullptr, nullptr, hdst, NN, 768);
  }
}